// Round 8
// baseline (312.853 us; speedup 1.0000x reference)
//
#include <hip/hip_runtime.h>
#include <math.h>

// Problem constants: B=4, N=65536, IN=2, OUT=512, C=64, H=32, W=32, W0=30
#define SIREN_W0 30.0f

typedef float f32x4 __attribute__((ext_vector_type(4)));
typedef float f32x2 __attribute__((ext_vector_type(2)));
typedef unsigned int u32;
typedef u32 u32x4 __attribute__((ext_vector_type(4)));

// cell = (b*32 + iy)*32 + ix, identical rounding/clip semantics to reference
__device__ __forceinline__ int cell_of(const float* __restrict__ x,
                                       const float* __restrict__ W_lin,
                                       const float* __restrict__ b_lin,
                                       int point)
{
    const f32x2 xv = *(const f32x2*)(x + (size_t)point * 2);
    const f32x4 wl = *(const f32x4*)W_lin;   // w00 w01 w10 w11
    const f32x2 bl = *(const f32x2*)b_lin;
    const float h0 = xv.x * wl.x + xv.y * wl.y + bl.x;
    const float h1 = xv.x * wl.z + xv.y * wl.w + bl.y;
    const float fx = (h0 + 1.0f) * 0.5f * 31.0f;
    const float fy = (h1 + 1.0f) * 0.5f * 31.0f;
    int ix = (int)rintf(fx); ix = ix < 0 ? 0 : (ix > 31 ? 31 : ix);
    int iy = (int)rintf(fy); iy = iy < 0 ? 0 : (iy > 31 ? 31 : iy);
    const int b = point >> 16;
    return ((b << 5) + iy) * 32 + ix;
}

// ---------------------------------------------------------------------------
// Kernel 1 (unchanged R4): combined[pos][o] = dots + b_shift[o] + b_vshift[o]
// ---------------------------------------------------------------------------
__global__ __launch_bounds__(256) void build_combined(
    const float* __restrict__ latent, const float* __restrict__ v,
    const float* __restrict__ W_shift, const float* __restrict__ b_shift,
    const float* __restrict__ W_vshift, const float* __restrict__ b_vshift,
    float* __restrict__ combined)
{
    __shared__ float featL[16][64];
    __shared__ float featV[16][64];
    const int pos0 = blockIdx.x * 16;
    const int b    = pos0 >> 10;
    const int rem  = pos0 & 1023;
    const int t    = threadIdx.x;

    const float* latBase = latent + (size_t)b * 65536 + rem;
    const float* vBase   = v      + (size_t)b * 65536 + rem;
#pragma unroll
    for (int k = 0; k < 4; ++k) {
        int e = t + k * 256;
        int c = e >> 4, p = e & 15;
        featL[p][c] = latBase[c * 1024 + p];
        featV[p][c] = vBase[c * 1024 + p];
    }
    __syncthreads();

    const int og = t & 127;
    const int pg = t >> 7;
    const int o0 = og * 4;
    const int p0 = pg * 8;

    float acc[8][4];
#pragma unroll
    for (int j = 0; j < 4; ++j) {
        float binit = b_shift[o0 + j] + b_vshift[o0 + j];
#pragma unroll
        for (int p = 0; p < 8; ++p) acc[p][j] = binit;
    }

    const f32x4* WS = (const f32x4*)(W_shift  + (size_t)o0 * 64);
    const f32x4* WV = (const f32x4*)(W_vshift + (size_t)o0 * 64);

#pragma unroll 4
    for (int c4 = 0; c4 < 16; ++c4) {
        f32x4 wS[4], wV[4];
#pragma unroll
        for (int j = 0; j < 4; ++j) {
            wS[j] = WS[j * 16 + c4];
            wV[j] = WV[j * 16 + c4];
        }
#pragma unroll
        for (int p = 0; p < 8; ++p) {
            f32x4 fL = *(const f32x4*)&featL[p0 + p][c4 * 4];
            f32x4 fV = *(const f32x4*)&featV[p0 + p][c4 * 4];
#pragma unroll
            for (int j = 0; j < 4; ++j) {
                acc[p][j] += fL.x * wS[j].x + fL.y * wS[j].y
                           + fL.z * wS[j].z + fL.w * wS[j].w
                           + fV.x * wV[j].x + fV.y * wV[j].y
                           + fV.z * wV[j].z + fV.w * wV[j].w;
            }
        }
    }

#pragma unroll
    for (int p = 0; p < 8; ++p) {
        f32x4 r = { acc[p][0], acc[p][1], acc[p][2], acc[p][3] };
        *(f32x4*)(combined + (size_t)(pos0 + p0 + p) * 512 + o0) = r;
    }
}

// --------------------------- counting sort passes ---------------------------
__global__ __launch_bounds__(256) void zero_counters(u32* __restrict__ buf)
{
    int i = blockIdx.x * 256 + threadIdx.x;   // 8192 entries: counts + cursors
    buf[i] = 0;
}

__global__ __launch_bounds__(256) void count_cells(
    const float* __restrict__ x, const float* __restrict__ W_lin,
    const float* __restrict__ b_lin, u32* __restrict__ counts)
{
    const int p = blockIdx.x * 256 + threadIdx.x;      // 262144 points
    atomicAdd(&counts[cell_of(x, W_lin, b_lin, p)], 1u);
}

__global__ __launch_bounds__(1024) void scan_cells(
    const u32* __restrict__ counts, u32* __restrict__ cursors)
{
    const int t = threadIdx.x;                 // 1024 threads, 4 cells each
    u32x4 c = ((const u32x4*)counts)[t];
    u32 tot = c.x + c.y + c.z + c.w;
    __shared__ u32 sc[1024];
    sc[t] = tot;
    __syncthreads();
#pragma unroll
    for (int off = 1; off < 1024; off <<= 1) {
        u32 v = (t >= off) ? sc[t - off] : 0u;
        __syncthreads();
        sc[t] += v;
        __syncthreads();
    }
    u32 base = sc[t] - tot;                    // exclusive prefix
    u32x4 s;
    s.x = base; s.y = s.x + c.x; s.z = s.y + c.y; s.w = s.z + c.z;
    ((u32x4*)cursors)[t] = s;
}

__global__ __launch_bounds__(256) void scatter_points(
    const float* __restrict__ x, const float* __restrict__ W_lin,
    const float* __restrict__ b_lin, u32* __restrict__ cursors,
    u32* __restrict__ sorted)
{
    const int p = blockIdx.x * 256 + threadIdx.x;
    const int cell = cell_of(x, W_lin, b_lin, p);
    const u32 slot = atomicAdd(&cursors[cell], 1u);
    sorted[slot] = (u32)p | ((u32)cell << 18);   // p < 2^18, cell < 2^12
}

// ---------------------------------------------------------------------------
// Main kernel: cell-sorted processing. Inner loop byte-identical to the
// 115.2us R4 kernel (bb load, __sinf, nontemporal stores, 32 thr/point);
// only the row derivation changed: cell comes packed in sorted[].
// Consecutive points share a cell -> combined row is L1-resident.
// ---------------------------------------------------------------------------
__global__ __launch_bounds__(256) void siren_out_sorted(
    const float* __restrict__ x, const float* __restrict__ W_lin,
    const float* __restrict__ b_lin, const float* __restrict__ combined,
    const u32* __restrict__ sorted, float* __restrict__ out)
{
    const int bid = blockIdx.x;
    const int pb  = (bid & 7) * 4096 + (bid >> 3);  // XCD-contiguous sorted range

    const int t    = threadIdx.x;
    const int lane = t & 31;
    const u32 entry = sorted[pb * 8 + (t >> 5)];
    const int p    = (int)(entry & 262143u);
    const int cell = (int)(entry >> 18);

    const f32x2 xv = *(const f32x2*)(x + (size_t)p * 2);

    const f32x4* crow = (const f32x4*)(combined + (size_t)cell * 512);
    const f32x4* Wl4  = (const f32x4*)W_lin;
    const f32x4* Bl4  = (const f32x4*)b_lin;
    f32x4* orow = ((f32x4*)out) + (size_t)p * 128;

#pragma unroll
    for (int k = 0; k < 4; ++k) {
        const int chunk = lane + k * 32;
        const f32x4 c4 = crow[chunk];
        const f32x4 wA = Wl4[chunk * 2];
        const f32x4 wB = Wl4[chunk * 2 + 1];
        const f32x4 bb = Bl4[chunk];

        f32x4 r;
        r.x = __sinf(SIREN_W0 * (xv.x * wA.x + xv.y * wA.y + bb.x + c4.x));
        r.y = __sinf(SIREN_W0 * (xv.x * wA.z + xv.y * wA.w + bb.y + c4.y));
        r.z = __sinf(SIREN_W0 * (xv.x * wB.x + xv.y * wB.y + bb.z + c4.z));
        r.w = __sinf(SIREN_W0 * (xv.x * wB.z + xv.y * wB.w + bb.w + c4.w));

        __builtin_nontemporal_store(r, orow + chunk);
    }
}

extern "C" void kernel_launch(void* const* d_in, const int* in_sizes, int n_in,
                              void* d_out, int out_size, void* d_ws, size_t ws_size,
                              hipStream_t stream) {
    const float* x        = (const float*)d_in[0];
    const float* latent   = (const float*)d_in[1];
    const float* v        = (const float*)d_in[2];
    const float* W_lin    = (const float*)d_in[3];
    const float* b_lin    = (const float*)d_in[4];
    const float* W_shift  = (const float*)d_in[5];
    const float* b_shift  = (const float*)d_in[6];
    const float* W_vshift = (const float*)d_in[7];
    const float* b_vshift = (const float*)d_in[8];
    float* out = (float*)d_out;

    // ws layout: combined 8 MiB | counts 16 KiB | cursors 16 KiB | sorted 1 MiB
    char* ws = (char*)d_ws;
    float* combined = (float*)ws;
    u32*   counts   = (u32*)(ws + (8u << 20));
    u32*   cursors  = (u32*)(ws + (8u << 20) + (16u << 10));
    u32*   sorted   = (u32*)(ws + (8u << 20) + (64u << 10));

    zero_counters <<<32,    256, 0, stream>>>(counts);   // counts+cursors (8192 u32, contiguous)
    build_combined<<<256,   256, 0, stream>>>(latent, v, W_shift, b_shift,
                                              W_vshift, b_vshift, combined);
    count_cells   <<<1024,  256, 0, stream>>>(x, W_lin, b_lin, counts);
    scan_cells    <<<1,    1024, 0, stream>>>(counts, cursors);
    scatter_points<<<1024,  256, 0, stream>>>(x, W_lin, b_lin, cursors, sorted);
    siren_out_sorted<<<32768, 256, 0, stream>>>(x, W_lin, b_lin, combined,
                                                sorted, out);
}

// Round 9
// 136.308 us; speedup vs baseline: 2.2952x; 2.2952x over previous
//
#include <hip/hip_runtime.h>
#include <math.h>

// Problem constants: B=4, N=65536, IN=2, OUT=512, C=64, H=32, W=32, W0=30
#define SIREN_W0 30.0f

typedef float f32x4 __attribute__((ext_vector_type(4)));
typedef float f32x2 __attribute__((ext_vector_type(2)));

// ---------------------------------------------------------------------------
// Kernel 1 (unchanged R4): combined[pos][o] = dots + b_shift[o] + b_vshift[o]
// Both reference gathers use the SAME (iy,ix) -> one combined map suffices.
// ---------------------------------------------------------------------------
__global__ __launch_bounds__(256) void build_combined(
    const float* __restrict__ latent, const float* __restrict__ v,
    const float* __restrict__ W_shift, const float* __restrict__ b_shift,
    const float* __restrict__ W_vshift, const float* __restrict__ b_vshift,
    float* __restrict__ combined)
{
    __shared__ float featL[16][64];
    __shared__ float featV[16][64];
    const int pos0 = blockIdx.x * 16;
    const int b    = pos0 >> 10;
    const int rem  = pos0 & 1023;
    const int t    = threadIdx.x;

    const float* latBase = latent + (size_t)b * 65536 + rem;
    const float* vBase   = v      + (size_t)b * 65536 + rem;
#pragma unroll
    for (int k = 0; k < 4; ++k) {
        int e = t + k * 256;
        int c = e >> 4, p = e & 15;
        featL[p][c] = latBase[c * 1024 + p];
        featV[p][c] = vBase[c * 1024 + p];
    }
    __syncthreads();

    const int og = t & 127;
    const int pg = t >> 7;
    const int o0 = og * 4;
    const int p0 = pg * 8;

    float acc[8][4];
#pragma unroll
    for (int j = 0; j < 4; ++j) {
        float binit = b_shift[o0 + j] + b_vshift[o0 + j];
#pragma unroll
        for (int p = 0; p < 8; ++p) acc[p][j] = binit;
    }

    const f32x4* WS = (const f32x4*)(W_shift  + (size_t)o0 * 64);
    const f32x4* WV = (const f32x4*)(W_vshift + (size_t)o0 * 64);

#pragma unroll 4
    for (int c4 = 0; c4 < 16; ++c4) {
        f32x4 wS[4], wV[4];
#pragma unroll
        for (int j = 0; j < 4; ++j) {
            wS[j] = WS[j * 16 + c4];
            wV[j] = WV[j * 16 + c4];
        }
#pragma unroll
        for (int p = 0; p < 8; ++p) {
            f32x4 fL = *(const f32x4*)&featL[p0 + p][c4 * 4];
            f32x4 fV = *(const f32x4*)&featV[p0 + p][c4 * 4];
#pragma unroll
            for (int j = 0; j < 4; ++j) {
                acc[p][j] += fL.x * wS[j].x + fL.y * wS[j].y
                           + fL.z * wS[j].z + fL.w * wS[j].w
                           + fV.x * wV[j].x + fV.y * wV[j].y
                           + fV.z * wV[j].z + fV.w * wV[j].w;
            }
        }
    }

#pragma unroll
    for (int p = 0; p < 8; ++p) {
        f32x4 r = { acc[p][0], acc[p][1], acc[p][2], acc[p][3] };
        *(f32x4*)(combined + (size_t)(pos0 + p0 + p) * 512 + o0) = r;
    }
}

// ---------------------------------------------------------------------------
// Kernel 2 (restructured): thread <-> one chunk, iterating 8 points.
//   chunk = tid & 127, point-group = tid >> 7; block = 16 points; NATURAL
//   point order (R8 lesson: write order owns the layout). Weights wA/wB/bb
//   loaded ONCE per thread (was: once per point) -> L1 read traffic /4,
//   VMEM instructions per KB stored ~5 -> ~2.3.
// Per point per wave: 1 broadcast xv load + 1 contiguous 1KB c4 load
//   + 1 contiguous 1KB nontemporal store. Math identical to R4.
// ---------------------------------------------------------------------------
__global__ __launch_bounds__(256) void siren_out(
    const float* __restrict__ x, const float* __restrict__ W_lin,
    const float* __restrict__ b_lin, const float* __restrict__ combined,
    float* __restrict__ out)
{
    const int t     = threadIdx.x;
    const int chunk = t & 127;
    const int pg    = t >> 7;                      // 0 or 1
    const int p0    = blockIdx.x * 16 + pg * 8;    // 8 consecutive points

    const f32x4* Wl4 = (const f32x4*)W_lin;
    const f32x4 wA = Wl4[chunk * 2];
    const f32x4 wB = Wl4[chunk * 2 + 1];
    const f32x4 bb = ((const f32x4*)b_lin)[chunk];

    // coordinate rows (first 4 floats of W_lin / first 2 of b_lin)
    const f32x4 wl = *(const f32x4*)W_lin;
    const f32x2 bl = *(const f32x2*)b_lin;

    const int b = p0 >> 16;   // batch constant across the 8 points (16 | 65536)
    const f32x4* cbase = (const f32x4*)(combined + (size_t)(b << 10) * 512);

#pragma unroll
    for (int i = 0; i < 8; ++i) {
        const int p = p0 + i;
        const f32x2 xv = *(const f32x2*)(x + (size_t)p * 2);

        const float h0 = xv.x * wl.x + xv.y * wl.y + bl.x;
        const float h1 = xv.x * wl.z + xv.y * wl.w + bl.y;
        const float fx = (h0 + 1.0f) * 0.5f * 31.0f;
        const float fy = (h1 + 1.0f) * 0.5f * 31.0f;
        int ix = (int)rintf(fx); ix = ix < 0 ? 0 : (ix > 31 ? 31 : ix);
        int iy = (int)rintf(fy); iy = iy < 0 ? 0 : (iy > 31 ? 31 : iy);

        const f32x4 c4 = cbase[(size_t)(iy * 32 + ix) * 128 + chunk];

        f32x4 r;
        r.x = __sinf(SIREN_W0 * (xv.x * wA.x + xv.y * wA.y + bb.x + c4.x));
        r.y = __sinf(SIREN_W0 * (xv.x * wA.z + xv.y * wA.w + bb.y + c4.y));
        r.z = __sinf(SIREN_W0 * (xv.x * wB.x + xv.y * wB.y + bb.z + c4.z));
        r.w = __sinf(SIREN_W0 * (xv.x * wB.z + xv.y * wB.w + bb.w + c4.w));

        __builtin_nontemporal_store(r, ((f32x4*)out) + (size_t)p * 128 + chunk);
    }
}

extern "C" void kernel_launch(void* const* d_in, const int* in_sizes, int n_in,
                              void* d_out, int out_size, void* d_ws, size_t ws_size,
                              hipStream_t stream) {
    const float* x        = (const float*)d_in[0];
    const float* latent   = (const float*)d_in[1];
    const float* v        = (const float*)d_in[2];
    const float* W_lin    = (const float*)d_in[3];
    const float* b_lin    = (const float*)d_in[4];
    const float* W_shift  = (const float*)d_in[5];
    const float* b_shift  = (const float*)d_in[6];
    const float* W_vshift = (const float*)d_in[7];
    const float* b_vshift = (const float*)d_in[8];
    float* out      = (float*)d_out;
    float* combined = (float*)d_ws;   // 8 MiB of d_ws

    build_combined<<<256, 256, 0, stream>>>(latent, v, W_shift, b_shift,
                                            W_vshift, b_vshift, combined);

    // 262144 points / 16 per block = 16384 blocks
    siren_out<<<16384, 256, 0, stream>>>(x, W_lin, b_lin, combined, out);
}

// Round 10
// 131.454 us; speedup vs baseline: 2.3799x; 1.0369x over previous
//
#include <hip/hip_runtime.h>
#include <math.h>

// Problem constants: B=4, N=65536, IN=2, OUT=512, C=64, H=32, W=32, W0=30
#define SIREN_W0 30.0f

typedef float f32x4 __attribute__((ext_vector_type(4)));
typedef float f32x2 __attribute__((ext_vector_type(2)));

// ---------------------------------------------------------------------------
// Kernel 1 (unchanged R4): combined[pos][o] = dots + b_shift[o] + b_vshift[o]
// Both reference gathers use the SAME (iy,ix) -> one combined map suffices.
// ---------------------------------------------------------------------------
__global__ __launch_bounds__(256) void build_combined(
    const float* __restrict__ latent, const float* __restrict__ v,
    const float* __restrict__ W_shift, const float* __restrict__ b_shift,
    const float* __restrict__ W_vshift, const float* __restrict__ b_vshift,
    float* __restrict__ combined)
{
    __shared__ float featL[16][64];
    __shared__ float featV[16][64];
    const int pos0 = blockIdx.x * 16;
    const int b    = pos0 >> 10;
    const int rem  = pos0 & 1023;
    const int t    = threadIdx.x;

    const float* latBase = latent + (size_t)b * 65536 + rem;
    const float* vBase   = v      + (size_t)b * 65536 + rem;
#pragma unroll
    for (int k = 0; k < 4; ++k) {
        int e = t + k * 256;
        int c = e >> 4, p = e & 15;
        featL[p][c] = latBase[c * 1024 + p];
        featV[p][c] = vBase[c * 1024 + p];
    }
    __syncthreads();

    const int og = t & 127;
    const int pg = t >> 7;
    const int o0 = og * 4;
    const int p0 = pg * 8;

    float acc[8][4];
#pragma unroll
    for (int j = 0; j < 4; ++j) {
        float binit = b_shift[o0 + j] + b_vshift[o0 + j];
#pragma unroll
        for (int p = 0; p < 8; ++p) acc[p][j] = binit;
    }

    const f32x4* WS = (const f32x4*)(W_shift  + (size_t)o0 * 64);
    const f32x4* WV = (const f32x4*)(W_vshift + (size_t)o0 * 64);

#pragma unroll 4
    for (int c4 = 0; c4 < 16; ++c4) {
        f32x4 wS[4], wV[4];
#pragma unroll
        for (int j = 0; j < 4; ++j) {
            wS[j] = WS[j * 16 + c4];
            wV[j] = WV[j * 16 + c4];
        }
#pragma unroll
        for (int p = 0; p < 8; ++p) {
            f32x4 fL = *(const f32x4*)&featL[p0 + p][c4 * 4];
            f32x4 fV = *(const f32x4*)&featV[p0 + p][c4 * 4];
#pragma unroll
            for (int j = 0; j < 4; ++j) {
                acc[p][j] += fL.x * wS[j].x + fL.y * wS[j].y
                           + fL.z * wS[j].z + fL.w * wS[j].w
                           + fV.x * wV[j].x + fV.y * wV[j].y
                           + fV.z * wV[j].z + fV.w * wV[j].w;
            }
        }
    }

#pragma unroll
    for (int p = 0; p < 8; ++p) {
        f32x4 r = { acc[p][0], acc[p][1], acc[p][2], acc[p][3] };
        *(f32x4*)(combined + (size_t)(pos0 + p0 + p) * 512 + o0) = r;
    }
}

// ---------------------------------------------------------------------------
// Kernel 2: R4 thread geometry (32 threads/point, chunk = lane + k*32,
// identical store pattern) but each thread serves TWO points (p0, p0+8):
// both gather rows resolved up front, all 8 c4 loads issued before any sin,
// weights wA/wB/bb loaded once for both points. Doubles gather MLP (4->8)
// without changing write order/granularity. NT stores (R6: removing = +57%).
// ---------------------------------------------------------------------------
__global__ __launch_bounds__(256) void siren_out(
    const float* __restrict__ x, const float* __restrict__ W_lin,
    const float* __restrict__ b_lin, const float* __restrict__ combined,
    float* __restrict__ out)
{
    const int t    = threadIdx.x;
    const int lane = t & 31;
    const int pg   = t >> 5;                      // 0..7
    const int pA   = blockIdx.x * 16 + pg;        // first point
    const int pB   = pA + 8;                      // second point
    const int b    = pA >> 16;                    // same batch (16 | 65536)

    // coordinate rows (first 4 floats of W_lin / first 2 of b_lin)
    const f32x4 wl = *(const f32x4*)W_lin;
    const f32x2 bl = *(const f32x2*)b_lin;
    const float* cb = combined + ((size_t)b << 10) * 512;

    const f32x2 xvA = *(const f32x2*)(x + (size_t)pA * 2);
    const f32x2 xvB = *(const f32x2*)(x + (size_t)pB * 2);

    float h0, h1, fx, fy; int ix, iy;

    h0 = xvA.x * wl.x + xvA.y * wl.y + bl.x;
    h1 = xvA.x * wl.z + xvA.y * wl.w + bl.y;
    fx = (h0 + 1.0f) * 0.5f * 31.0f;
    fy = (h1 + 1.0f) * 0.5f * 31.0f;
    ix = (int)rintf(fx); ix = ix < 0 ? 0 : (ix > 31 ? 31 : ix);
    iy = (int)rintf(fy); iy = iy < 0 ? 0 : (iy > 31 ? 31 : iy);
    const f32x4* crowA = (const f32x4*)(cb + (size_t)(iy * 32 + ix) * 512);

    h0 = xvB.x * wl.x + xvB.y * wl.y + bl.x;
    h1 = xvB.x * wl.z + xvB.y * wl.w + bl.y;
    fx = (h0 + 1.0f) * 0.5f * 31.0f;
    fy = (h1 + 1.0f) * 0.5f * 31.0f;
    ix = (int)rintf(fx); ix = ix < 0 ? 0 : (ix > 31 ? 31 : ix);
    iy = (int)rintf(fy); iy = iy < 0 ? 0 : (iy > 31 ? 31 : iy);
    const f32x4* crowB = (const f32x4*)(cb + (size_t)(iy * 32 + ix) * 512);

    // issue all 8 gather loads before any compute
    f32x4 cA[4], cB[4];
#pragma unroll
    for (int k = 0; k < 4; ++k) cA[k] = crowA[lane + k * 32];
#pragma unroll
    for (int k = 0; k < 4; ++k) cB[k] = crowB[lane + k * 32];

    const f32x4* Wl4 = (const f32x4*)W_lin;
    const f32x4* Bl4 = (const f32x4*)b_lin;
    f32x4* orowA = ((f32x4*)out) + (size_t)pA * 128;
    f32x4* orowB = ((f32x4*)out) + (size_t)pB * 128;

#pragma unroll
    for (int k = 0; k < 4; ++k) {
        const int chunk = lane + k * 32;
        const f32x4 wA = Wl4[chunk * 2];
        const f32x4 wB = Wl4[chunk * 2 + 1];
        const f32x4 bb = Bl4[chunk];

        f32x4 rA, rB;
        rA.x = __sinf(SIREN_W0 * (xvA.x * wA.x + xvA.y * wA.y + bb.x + cA[k].x));
        rA.y = __sinf(SIREN_W0 * (xvA.x * wA.z + xvA.y * wA.w + bb.y + cA[k].y));
        rA.z = __sinf(SIREN_W0 * (xvA.x * wB.x + xvA.y * wB.y + bb.z + cA[k].z));
        rA.w = __sinf(SIREN_W0 * (xvA.x * wB.z + xvA.y * wB.w + bb.w + cA[k].w));
        rB.x = __sinf(SIREN_W0 * (xvB.x * wA.x + xvB.y * wA.y + bb.x + cB[k].x));
        rB.y = __sinf(SIREN_W0 * (xvB.x * wA.z + xvB.y * wA.w + bb.y + cB[k].y));
        rB.z = __sinf(SIREN_W0 * (xvB.x * wB.x + xvB.y * wB.y + bb.z + cB[k].z));
        rB.w = __sinf(SIREN_W0 * (xvB.x * wB.z + xvB.y * wB.w + bb.w + cB[k].w));

        __builtin_nontemporal_store(rA, orowA + chunk);
        __builtin_nontemporal_store(rB, orowB + chunk);
    }
}

extern "C" void kernel_launch(void* const* d_in, const int* in_sizes, int n_in,
                              void* d_out, int out_size, void* d_ws, size_t ws_size,
                              hipStream_t stream) {
    const float* x        = (const float*)d_in[0];
    const float* latent   = (const float*)d_in[1];
    const float* v        = (const float*)d_in[2];
    const float* W_lin    = (const float*)d_in[3];
    const float* b_lin    = (const float*)d_in[4];
    const float* W_shift  = (const float*)d_in[5];
    const float* b_shift  = (const float*)d_in[6];
    const float* W_vshift = (const float*)d_in[7];
    const float* b_vshift = (const float*)d_in[8];
    float* out      = (float*)d_out;
    float* combined = (float*)d_ws;   // 8 MiB of d_ws

    build_combined<<<256, 256, 0, stream>>>(latent, v, W_shift, b_shift,
                                            W_vshift, b_vshift, combined);

    // 262144 points / 16 per block = 16384 blocks
    siren_out<<<16384, 256, 0, stream>>>(x, W_lin, b_lin, combined, out);
}

// Round 11
// 114.616 us; speedup vs baseline: 2.7296x; 1.1469x over previous
//
#include <hip/hip_runtime.h>
#include <math.h>

// Problem constants: B=4, N=65536, IN=2, OUT=512, C=64, H=32, W=32, W0=30
#define SIREN_W0 30.0f

typedef float f32x4 __attribute__((ext_vector_type(4)));
typedef float f32x2 __attribute__((ext_vector_type(2)));

// ---------------------------------------------------------------------------
// Kernel 1 (unchanged R4): combined[pos][o] = dots + b_shift[o] + b_vshift[o]
// Both reference gathers use the SAME (iy,ix) -> one combined map suffices.
// ---------------------------------------------------------------------------
__global__ __launch_bounds__(256) void build_combined(
    const float* __restrict__ latent, const float* __restrict__ v,
    const float* __restrict__ W_shift, const float* __restrict__ b_shift,
    const float* __restrict__ W_vshift, const float* __restrict__ b_vshift,
    float* __restrict__ combined)
{
    __shared__ float featL[16][64];
    __shared__ float featV[16][64];
    const int pos0 = blockIdx.x * 16;
    const int b    = pos0 >> 10;
    const int rem  = pos0 & 1023;
    const int t    = threadIdx.x;

    const float* latBase = latent + (size_t)b * 65536 + rem;
    const float* vBase   = v      + (size_t)b * 65536 + rem;
#pragma unroll
    for (int k = 0; k < 4; ++k) {
        int e = t + k * 256;
        int c = e >> 4, p = e & 15;
        featL[p][c] = latBase[c * 1024 + p];
        featV[p][c] = vBase[c * 1024 + p];
    }
    __syncthreads();

    const int og = t & 127;
    const int pg = t >> 7;
    const int o0 = og * 4;
    const int p0 = pg * 8;

    float acc[8][4];
#pragma unroll
    for (int j = 0; j < 4; ++j) {
        float binit = b_shift[o0 + j] + b_vshift[o0 + j];
#pragma unroll
        for (int p = 0; p < 8; ++p) acc[p][j] = binit;
    }

    const f32x4* WS = (const f32x4*)(W_shift  + (size_t)o0 * 64);
    const f32x4* WV = (const f32x4*)(W_vshift + (size_t)o0 * 64);

#pragma unroll 4
    for (int c4 = 0; c4 < 16; ++c4) {
        f32x4 wS[4], wV[4];
#pragma unroll
        for (int j = 0; j < 4; ++j) {
            wS[j] = WS[j * 16 + c4];
            wV[j] = WV[j * 16 + c4];
        }
#pragma unroll
        for (int p = 0; p < 8; ++p) {
            f32x4 fL = *(const f32x4*)&featL[p0 + p][c4 * 4];
            f32x4 fV = *(const f32x4*)&featV[p0 + p][c4 * 4];
#pragma unroll
            for (int j = 0; j < 4; ++j) {
                acc[p][j] += fL.x * wS[j].x + fL.y * wS[j].y
                           + fL.z * wS[j].z + fL.w * wS[j].w
                           + fV.x * wV[j].x + fV.y * wV[j].y
                           + fV.z * wV[j].z + fV.w * wV[j].w;
            }
        }
    }

#pragma unroll
    for (int p = 0; p < 8; ++p) {
        f32x4 r = { acc[p][0], acc[p][1], acc[p][2], acc[p][3] };
        *(f32x4*)(combined + (size_t)(pos0 + p0 + p) * 512 + o0) = r;
    }
}

// ---------------------------------------------------------------------------
// Kernel 2: BYTE-IDENTICAL body to the 115.2us R4 kernel (32 threads/point,
// 4 chunks/thread, bb load, __sinf, nt stores, XCD swizzle). The ONLY change
// this round is at the launch site: 48 KB dynamic-LDS ballast caps occupancy
// at 3 blocks/CU (12 waves/CU) to reduce concurrent write-stream count.
// ---------------------------------------------------------------------------
__global__ __launch_bounds__(256) void siren_out(
    const float* __restrict__ x, const float* __restrict__ W_lin,
    const float* __restrict__ b_lin, const float* __restrict__ combined,
    float* __restrict__ out)
{
    const int bid = blockIdx.x;
    const int xcd = bid & 7;
    const int idx = bid >> 3;
    const int pb  = ((xcd >> 1) << 13) + ((xcd & 1) << 12) + idx;

    const int tid   = pb * 256 + threadIdx.x;
    const int point = tid >> 5;
    const int lane  = tid & 31;
    const int b     = point >> 16;

    const f32x2 xv = *(const f32x2*)(x + (size_t)point * 2);

    const f32x4 wl = *(const f32x4*)W_lin;
    const f32x2 bl = *(const f32x2*)b_lin;
    const float h0 = xv.x * wl.x + xv.y * wl.y + bl.x;
    const float h1 = xv.x * wl.z + xv.y * wl.w + bl.y;

    const float fx = (h0 + 1.0f) * 0.5f * 31.0f;
    const float fy = (h1 + 1.0f) * 0.5f * 31.0f;
    int ix = (int)rintf(fx); ix = ix < 0 ? 0 : (ix > 31 ? 31 : ix);
    int iy = (int)rintf(fy); iy = iy < 0 ? 0 : (iy > 31 ? 31 : iy);

    const f32x4* crow =
        (const f32x4*)(combined + (size_t)(((b << 5) + iy) * 32 + ix) * 512);
    const f32x4* Wl4 = (const f32x4*)W_lin;
    const f32x4* Bl4 = (const f32x4*)b_lin;
    f32x4* orow = ((f32x4*)out) + (size_t)point * 128;

#pragma unroll
    for (int k = 0; k < 4; ++k) {
        const int chunk = lane + k * 32;
        const f32x4 c4 = crow[chunk];
        const f32x4 wA = Wl4[chunk * 2];
        const f32x4 wB = Wl4[chunk * 2 + 1];
        const f32x4 bb = Bl4[chunk];

        f32x4 r;
        r.x = __sinf(SIREN_W0 * (xv.x * wA.x + xv.y * wA.y + bb.x + c4.x));
        r.y = __sinf(SIREN_W0 * (xv.x * wA.z + xv.y * wA.w + bb.y + c4.y));
        r.z = __sinf(SIREN_W0 * (xv.x * wB.x + xv.y * wB.y + bb.z + c4.z));
        r.w = __sinf(SIREN_W0 * (xv.x * wB.z + xv.y * wB.w + bb.w + c4.w));

        __builtin_nontemporal_store(r, orow + chunk);
    }
}

extern "C" void kernel_launch(void* const* d_in, const int* in_sizes, int n_in,
                              void* d_out, int out_size, void* d_ws, size_t ws_size,
                              hipStream_t stream) {
    const float* x        = (const float*)d_in[0];
    const float* latent   = (const float*)d_in[1];
    const float* v        = (const float*)d_in[2];
    const float* W_lin    = (const float*)d_in[3];
    const float* b_lin    = (const float*)d_in[4];
    const float* W_shift  = (const float*)d_in[5];
    const float* b_shift  = (const float*)d_in[6];
    const float* W_vshift = (const float*)d_in[7];
    const float* b_vshift = (const float*)d_in[8];
    float* out      = (float*)d_out;
    float* combined = (float*)d_ws;   // 8 MiB of d_ws

    build_combined<<<256, 256, 0, stream>>>(latent, v, W_shift, b_shift,
                                            W_vshift, b_vshift, combined);

    // 48 KB dynamic-LDS ballast (unreferenced; allocated from the dispatch
    // packet) -> 3 blocks/CU = 12 waves/CU occupancy cap. Body unchanged.
    siren_out<<<32768, 256, 49152, stream>>>(x, W_lin, b_lin, combined, out);
}